// Round 6
// baseline (370.119 us; speedup 1.0000x reference)
//
#include <hip/hip_runtime.h>

#define T_TOK 4096
#define H_DIM 512
#define I_DIM 1024
#define E_NUM 32
#define KTOP  2
#define CAP   512
#define NROWS (E_NUM * CAP)    // 16384
#define NPAIR (T_TOK * KTOP)   // 8192

typedef __attribute__((ext_vector_type(8))) short short8;    // 8 bf16 = 4 VGPRs
typedef __attribute__((ext_vector_type(4))) float float4v;
typedef __attribute__((ext_vector_type(4))) unsigned int uint4v;

__device__ __forceinline__ unsigned short f2bf_rne(float f) {
  unsigned int u = __float_as_uint(f);
  u += 0x7FFFu + ((u >> 16) & 1u);
  return (unsigned short)(u >> 16);
}
__device__ __forceinline__ unsigned int pack_bf2(float a, float b) {
  return (unsigned int)f2bf_rne(a) | ((unsigned int)f2bf_rne(b) << 16);
}
__device__ __forceinline__ float bf2f(unsigned short s) {
  return __uint_as_float(((unsigned int)s) << 16);
}

#define GLOAD_LDS16(gptr, lptr)                                                         \
  __builtin_amdgcn_global_load_lds((const __attribute__((address_space(1))) unsigned int*)(gptr), \
                                   (__attribute__((address_space(3))) unsigned int*)(lptr), 16, 0, 0)

// ---------------- routing ----------------
__global__ void k_route(const int* __restrict__ idx, int* __restrict__ counts,
                        int* __restrict__ slot_token, int* __restrict__ inv) {
  int i = blockIdx.x * 256 + threadIdx.x;
  if (i >= NPAIR) return;
  int e = idx[i];
  int p = atomicAdd(counts + e, 1);
  if (p < CAP) {
    slot_token[e * CAP + p] = i >> 1;  // KTOP == 2
    inv[i] = e * CAP + p;
  } else {
    inv[i] = -1;
  }
}

// ---------------- gather tokens -> bf16 dispatch buffer (early-exit padded rows) ----
__global__ void k_gather(const float* __restrict__ hs, const int* __restrict__ counts,
                         const int* __restrict__ slot_token, unsigned short* __restrict__ xd) {
  const int r = blockIdx.x * 4 + (threadIdx.x >> 6);  // one wave per row
  const int lane = threadIdx.x & 63;
  const int e = r >> 9;
  const int p = r & (CAP - 1);
  const int cnt = min(counts[e], CAP);
  if (p >= ((cnt + 127) & ~127)) return;  // beyond last active tile: never read
  uint4v v = {0u, 0u, 0u, 0u};
  if (p < cnt) {
    const int t = slot_token[r];
    const float4v* src = (const float4v*)(hs + (size_t)t * H_DIM);
    float4v f0 = src[lane * 2];
    float4v f1 = src[lane * 2 + 1];
    v.x = pack_bf2(f0.x, f0.y);
    v.y = pack_bf2(f0.z, f0.w);
    v.z = pack_bf2(f1.x, f1.y);
    v.w = pack_bf2(f1.z, f1.w);
  }
  *(uint4v*)(xd + (size_t)r * H_DIM + lane * 8) = v;
}

// ---------------- weight convert to PRE-TILED bf16 ----------------
// wb1[e][cb(16)][t(16)][m(2)][chunk(256)][8]: chunk = kc*64+n holds
// w[e][m*I + cb*64+n][t*32 + kc*8 .. +8]. One 4KB tile per (e,cb,t,m) ->
// GEMM1 stages each B matrix with a single coalesced global_load_lds.
__global__ void k_wconv1(const float* __restrict__ gup, unsigned short* __restrict__ wb1) {
  const int b = blockIdx.x;              // 1024 = 32e x 16cb x 2m
  const int m = b & 1, cb = (b >> 1) & 15, e = b >> 5;
  const int tid = threadIdx.x;
  const int kc = tid >> 6, n = tid & 63;
  const float* src = gup + ((size_t)e * 2 * I_DIM + (size_t)m * I_DIM + cb * 64 + n) * H_DIM + kc * 8;
  unsigned short* dst = wb1 + ((((size_t)(e * 16 + cb) * 16) * 2 + m) * 2048) + (size_t)(kc * 64 + n) * 8;
#pragma unroll 4
  for (int t = 0; t < 16; ++t) {
    float4v f0 = *(const float4v*)(src + t * 32);
    float4v f1 = *(const float4v*)(src + t * 32 + 4);
    uint4v v;
    v.x = pack_bf2(f0.x, f0.y); v.y = pack_bf2(f0.z, f0.w);
    v.z = pack_bf2(f1.x, f1.y); v.w = pack_bf2(f1.z, f1.w);
    *(uint4v*)(dst + (size_t)t * 4096) = v;
  }
}

// wb2[e][cb(8)][t(32)][chunk(256)][8]: chunk = kc*64+n holds dwn[e][cb*64+n][t*32+kc*8..+8]
__global__ void k_wconv2(const float* __restrict__ dwn, unsigned short* __restrict__ wb2) {
  const int b = blockIdx.x;              // 512 = 32e x 8cb x 2half
  const int half = b & 1, cb = (b >> 1) & 7, e = b >> 4;
  const int tid = threadIdx.x;
  const int kc = tid >> 6, n = tid & 63;
  const float* src = dwn + ((size_t)e * H_DIM + cb * 64 + n) * I_DIM + kc * 8;
  unsigned short* dst = wb2 + ((size_t)(e * 8 + cb) * 32) * 2048 + (size_t)(kc * 64 + n) * 8;
#pragma unroll 4
  for (int tt = 0; tt < 16; ++tt) {
    int t = half * 16 + tt;
    float4v f0 = *(const float4v*)(src + t * 32);
    float4v f1 = *(const float4v*)(src + t * 32 + 4);
    uint4v v;
    v.x = pack_bf2(f0.x, f0.y); v.y = pack_bf2(f0.z, f0.w);
    v.z = pack_bf2(f1.x, f1.y); v.w = pack_bf2(f1.z, f1.w);
    *(uint4v*)(dst + (size_t)t * 2048) = v;
  }
}

// ---------------- GEMM1: xd[NROWS,H] x wb1 -> silu(g)*u -> act[NROWS,I] ----
// 128x64 tile. A (2 loads) + Bg (1) + Bu (1) all via global_load_lds, pre-tiled
// bf16 B. Depth-4 counted-vmcnt pipeline: 5 x 16KB buffers = 80KB -> 2 blocks/CU.
__global__ __launch_bounds__(256, 2) void k_gemm1(const unsigned short* __restrict__ xd,
                                                  const unsigned short* __restrict__ wb1,
                                                  const int* __restrict__ counts,
                                                  unsigned short* __restrict__ act) {
  __shared__ unsigned short lds[5 * 8192];  // per buf: A[0,4096) Bg[4096,6144) Bu[6144,8192)

  // expert<->XCD affinity (hw: wg i -> XCD i%8). 256 slots/XCD = 4e x 16cb x 4rt.
  const int bid = blockIdx.x;                      // 2048 blocks
  const int xcd = bid & 7, slot = bid >> 3;        // slot 0..255
  const int e = xcd + 8 * (slot >> 6);
  const int sub = slot & 63;
  const int c0 = (sub & 15) * 64;
  const int rt = sub >> 4;                         // 0..3
  const int cnt = min(counts[e], CAP);
  if (rt * 128 >= cnt) return;
  const int r0 = e * CAP + rt * 128;

  const int tid = threadIdx.x;
  const int lane = tid & 63;
  const int wid = tid >> 6;
  const int wr = wid >> 1, wc = wid & 1;   // wave tile: 64 rows x 32 cols
  const int ml = lane & 15, kg = lane >> 4;

  const int rowA = tid & 127, kcA = tid >> 7;
  const unsigned short* a_src = xd + (size_t)(r0 + rowA) * H_DIM + kcA * 8;
  const unsigned short* wbC = wb1 + (size_t)(e * 16 + (sub & 15)) * 65536 + (size_t)tid * 8;
  const int dA0 = (wid * 64) * 8;          // wave-uniform LDS bases; DMA adds lane*16B
  const int dA1 = (256 + wid * 64) * 8;
  const int dBg = 4096 + (wid * 64) * 8;
  const int dBu = 6144 + (wid * 64) * 8;

  float4v accg[4][2] = {};
  float4v accu[4][2] = {};

  auto STAGE = [&](unsigned short* lb, int t) {
    GLOAD_LDS16(a_src + t * 32, lb + dA0);
    GLOAD_LDS16(a_src + t * 32 + 16, lb + dA1);
    GLOAD_LDS16(wbC + (size_t)t * 4096, lb + dBg);         // gate tile (4KB contiguous)
    GLOAD_LDS16(wbC + (size_t)t * 4096 + 2048, lb + dBu);  // up tile
  };
  auto COMPUTE = [&](const unsigned short* lb) {
    short8 af[4], bg[2], bu[2];
#pragma unroll
    for (int mi = 0; mi < 4; ++mi)
      af[mi] = *(const short8*)(lb + (kg * 128 + wr * 64 + mi * 16 + ml) * 8);
#pragma unroll
    for (int ni = 0; ni < 2; ++ni) {
      const int o = (kg * 64 + wc * 32 + ni * 16 + ml) * 8;
      bg[ni] = *(const short8*)(lb + 4096 + o);
      bu[ni] = *(const short8*)(lb + 6144 + o);
    }
#pragma unroll
    for (int mi = 0; mi < 4; ++mi)
#pragma unroll
      for (int ni = 0; ni < 2; ++ni) {
        accg[mi][ni] = __builtin_amdgcn_mfma_f32_16x16x32_bf16(af[mi], bg[ni], accg[mi][ni], 0, 0, 0);
        accu[mi][ni] = __builtin_amdgcn_mfma_f32_16x16x32_bf16(af[mi], bu[ni], accu[mi][ni], 0, 0, 0);
      }
  };

  unsigned short* p0 = lds;
  unsigned short* p1 = lds + 8192;
  unsigned short* p2 = lds + 16384;
  unsigned short* p3 = lds + 24576;
  unsigned short* p4 = lds + 32768;
  STAGE(p0, 0); STAGE(p1, 1); STAGE(p2, 2); STAGE(p3, 3);
#pragma unroll 1
  for (int t = 0; t < 12; ++t) {           // NT = 16; main body t=0..11
    asm volatile("s_waitcnt vmcnt(12)" ::: "memory");  // tile t landed; t+1..t+3 in flight
    __builtin_amdgcn_s_barrier();
    __builtin_amdgcn_sched_barrier(0);
    STAGE(p4, t + 4);                      // p4 was computed at t-1: safe past barrier
    COMPUTE(p0);
    unsigned short* tmp = p0; p0 = p1; p1 = p2; p2 = p3; p3 = p4; p4 = tmp;
  }
  asm volatile("s_waitcnt vmcnt(12)" ::: "memory");    // t = 12
  __builtin_amdgcn_s_barrier(); __builtin_amdgcn_sched_barrier(0);
  COMPUTE(p0);
  asm volatile("s_waitcnt vmcnt(8)" ::: "memory");     // t = 13
  __builtin_amdgcn_s_barrier(); __builtin_amdgcn_sched_barrier(0);
  COMPUTE(p1);
  asm volatile("s_waitcnt vmcnt(4)" ::: "memory");     // t = 14
  __builtin_amdgcn_s_barrier(); __builtin_amdgcn_sched_barrier(0);
  COMPUTE(p2);
  asm volatile("s_waitcnt vmcnt(0)" ::: "memory");     // t = 15 (drain)
  __builtin_amdgcn_s_barrier(); __builtin_amdgcn_sched_barrier(0);
  COMPUTE(p3);

  // epilogue: act = silu(g)*u, bf16
#pragma unroll
  for (int mi = 0; mi < 4; ++mi) {
    const int row = r0 + wr * 64 + mi * 16 + kg * 4;
#pragma unroll
    for (int ni = 0; ni < 2; ++ni) {
      const int col = c0 + wc * 32 + ni * 16 + ml;
#pragma unroll
      for (int rj = 0; rj < 4; ++rj) {
        float g = accg[mi][ni][rj];
        float u = accu[mi][ni][rj];
        float a = (g / (1.0f + __expf(-g))) * u;
        act[(size_t)(row + rj) * I_DIM + col] = f2bf_rne(a);
      }
    }
  }
}

// ---------------- GEMM2: act[NROWS,I] x wb2 -> yd[NROWS,H] bf16 ----
// Same structure: 3 loads/step, depth-4, 5 x 12KB buffers = 60KB -> 2 blocks/CU.
__global__ __launch_bounds__(256, 2) void k_gemm2(const unsigned short* __restrict__ act,
                                                  const unsigned short* __restrict__ wb2,
                                                  const int* __restrict__ counts,
                                                  unsigned short* __restrict__ yd) {
  __shared__ unsigned short lds[5 * 6144];  // per buf: A[0,4096) B[4096,6144)

  const int bid = blockIdx.x;                      // 1024 blocks
  const int xcd = bid & 7, slot = bid >> 3;        // slot 0..127
  const int e = xcd + 8 * (slot >> 5);
  const int sub = slot & 31;
  const int c0 = (sub & 7) * 64;
  const int rt = sub >> 3;                         // 0..3
  const int cnt = min(counts[e], CAP);
  if (rt * 128 >= cnt) return;
  const int r0 = e * CAP + rt * 128;

  const int tid = threadIdx.x;
  const int lane = tid & 63;
  const int wid = tid >> 6;
  const int wr = wid >> 1, wc = wid & 1;
  const int ml = lane & 15, kg = lane >> 4;

  const int rowA = tid & 127, kcA = tid >> 7;
  const unsigned short* a_src = act + (size_t)(r0 + rowA) * I_DIM + kcA * 8;
  const unsigned short* wbC = wb2 + (size_t)(e * 8 + (sub & 7)) * 65536 + (size_t)tid * 8;
  const int dA0 = (wid * 64) * 8;
  const int dA1 = (256 + wid * 64) * 8;
  const int dB  = 4096 + (wid * 64) * 8;

  float4v acc[4][2] = {};

  auto STAGE = [&](unsigned short* lb, int t) {
    GLOAD_LDS16(a_src + t * 32, lb + dA0);
    GLOAD_LDS16(a_src + t * 32 + 16, lb + dA1);
    GLOAD_LDS16(wbC + (size_t)t * 2048, lb + dB);
  };
  auto COMPUTE = [&](const unsigned short* lb) {
    short8 af[4], bf[2];
#pragma unroll
    for (int mi = 0; mi < 4; ++mi)
      af[mi] = *(const short8*)(lb + (kg * 128 + wr * 64 + mi * 16 + ml) * 8);
#pragma unroll
    for (int ni = 0; ni < 2; ++ni)
      bf[ni] = *(const short8*)(lb + 4096 + (kg * 64 + wc * 32 + ni * 16 + ml) * 8);
#pragma unroll
    for (int mi = 0; mi < 4; ++mi)
#pragma unroll
      for (int ni = 0; ni < 2; ++ni)
        acc[mi][ni] = __builtin_amdgcn_mfma_f32_16x16x32_bf16(af[mi], bf[ni], acc[mi][ni], 0, 0, 0);
  };

  unsigned short* p0 = lds;
  unsigned short* p1 = lds + 6144;
  unsigned short* p2 = lds + 12288;
  unsigned short* p3 = lds + 18432;
  unsigned short* p4 = lds + 24576;
  STAGE(p0, 0); STAGE(p1, 1); STAGE(p2, 2); STAGE(p3, 3);
#pragma unroll 1
  for (int t = 0; t < 28; ++t) {           // NT = 32; main body t=0..27
    asm volatile("s_waitcnt vmcnt(9)" ::: "memory");
    __builtin_amdgcn_s_barrier();
    __builtin_amdgcn_sched_barrier(0);
    STAGE(p4, t + 4);
    COMPUTE(p0);
    unsigned short* tmp = p0; p0 = p1; p1 = p2; p2 = p3; p3 = p4; p4 = tmp;
  }
  asm volatile("s_waitcnt vmcnt(9)" ::: "memory");     // t = 28
  __builtin_amdgcn_s_barrier(); __builtin_amdgcn_sched_barrier(0);
  COMPUTE(p0);
  asm volatile("s_waitcnt vmcnt(6)" ::: "memory");     // t = 29
  __builtin_amdgcn_s_barrier(); __builtin_amdgcn_sched_barrier(0);
  COMPUTE(p1);
  asm volatile("s_waitcnt vmcnt(3)" ::: "memory");     // t = 30
  __builtin_amdgcn_s_barrier(); __builtin_amdgcn_sched_barrier(0);
  COMPUTE(p2);
  asm volatile("s_waitcnt vmcnt(0)" ::: "memory");     // t = 31
  __builtin_amdgcn_s_barrier(); __builtin_amdgcn_sched_barrier(0);
  COMPUTE(p3);

#pragma unroll
  for (int mi = 0; mi < 4; ++mi) {
    const int row = r0 + wr * 64 + mi * 16 + kg * 4;
#pragma unroll
    for (int ni = 0; ni < 2; ++ni) {
      const int col = c0 + wc * 32 + ni * 16 + ml;
#pragma unroll
      for (int rj = 0; rj < 4; ++rj)
        yd[(size_t)(row + rj) * H_DIM + col] = f2bf_rne(acc[mi][ni][rj]);
    }
  }
}

// ---------------- combine: out[t] = sum_k w[t,k] * yd[inv[t,k]] ----------------
__global__ void k_combine(const unsigned short* __restrict__ yd, const int* __restrict__ inv,
                          const float* __restrict__ wts, float* __restrict__ out) {
  const int t = blockIdx.x * 4 + (threadIdx.x >> 6);  // one wave per token
  const int lane = threadIdx.x & 63;
  const int i0 = 2 * t, i1 = 2 * t + 1;
  const int r0 = inv[i0], r1 = inv[i1];
  float o[8] = {0.f, 0.f, 0.f, 0.f, 0.f, 0.f, 0.f, 0.f};
  if (r0 >= 0) {
    float w = wts[i0];
    short8 y = *(const short8*)(yd + (size_t)r0 * H_DIM + lane * 8);
#pragma unroll
    for (int j = 0; j < 8; ++j) o[j] += w * bf2f((unsigned short)y[j]);
  }
  if (r1 >= 0) {
    float w = wts[i1];
    short8 y = *(const short8*)(yd + (size_t)r1 * H_DIM + lane * 8);
#pragma unroll
    for (int j = 0; j < 8; ++j) o[j] += w * bf2f((unsigned short)y[j]);
  }
  float4v v0 = {o[0], o[1], o[2], o[3]};
  float4v v1 = {o[4], o[5], o[6], o[7]};
  float4v* dst = (float4v*)(out + (size_t)t * H_DIM + lane * 8);
  dst[0] = v0;
  dst[1] = v1;
}

extern "C" void kernel_launch(void* const* d_in, const int* in_sizes, int n_in,
                              void* d_out, int out_size, void* d_ws, size_t ws_size,
                              hipStream_t stream) {
  const float* hs  = (const float*)d_in[0];  // [T,H]
  const int*   idx = (const int*)d_in[1];    // [T,K]
  const float* wts = (const float*)d_in[2];  // [T,K]
  const float* gup = (const float*)d_in[3];  // [E,2I,H]
  const float* dwn = (const float*)d_in[4];  // [E,H,I]
  float* out = (float*)d_out;                // [T,H]

  char* ws = (char*)d_ws;
  int* counts       = (int*)ws;                             // 128 B used
  int* inv          = (int*)(ws + 1024);                    // 32 KB
  int* slot_token   = (int*)(ws + 1024 + 32768);            // 64 KB
  unsigned short* xd  = (unsigned short*)(ws + 131072);     // 16.8 MB
  unsigned short* act = xd + (size_t)NROWS * H_DIM;         // 33.6 MB
  unsigned short* yd  = xd;  // xd dead after gemm1; alias
  unsigned short* wb1 = act + (size_t)NROWS * I_DIM;        // 67 MB (tiled bf16 gate+up)
  unsigned short* wb2 = wb1 + (size_t)E_NUM * 2 * I_DIM * H_DIM;  // 33.6 MB (tiled bf16 down)

  hipMemsetAsync(counts, 0, E_NUM * sizeof(int), stream);
  k_wconv1<<<1024, 256, 0, stream>>>(gup, wb1);
  k_wconv2<<<512, 256, 0, stream>>>(dwn, wb2);
  k_route<<<NPAIR / 256, 256, 0, stream>>>(idx, counts, slot_token, inv);
  k_gather<<<NROWS / 4, 256, 0, stream>>>(hs, counts, slot_token, xd);
  k_gemm1<<<2048, 256, 0, stream>>>(xd, wb1, counts, act);   // XCD-affine 1D grid
  k_gemm2<<<1024, 256, 0, stream>>>(act, wb2, counts, yd);
  k_combine<<<T_TOK / 4, 256, 0, stream>>>(yd, inv, wts, out);
}